// Round 1
// baseline (302.051 us; speedup 1.0000x reference)
//
#include <hip/hip_runtime.h>
#include <hip/hip_bf16.h>
#include <stdint.h>

#define N_NODES 6144
#define IN_F    512
#define OUT_F   64
#define NH      8
#define ALPHA   0.2f
#define L2E     1.4426950408889634f
#define NTILES  (N_NODES / 64)   // 96

typedef __attribute__((ext_vector_type(8))) short bf16x8;
typedef __attribute__((ext_vector_type(4))) float f32x4;

__device__ __forceinline__ unsigned short f2bf(float f) {
    uint32_t u = __float_as_uint(f);
    u += 0x7fffu + ((u >> 16) & 1u);     // round-to-nearest-even
    return (unsigned short)(u >> 16);
}
__device__ __forceinline__ float bf2f(unsigned short h) {
    return __uint_as_float(((uint32_t)h) << 16);
}

// ---------------------------------------------------------------------------
// x (f32 [N, 512]) -> xh (bf16 hi) + xl (bf16 of residual), same layout
__global__ __launch_bounds__(256) void k_convert_x(
    const float* __restrict__ x, unsigned short* __restrict__ xh,
    unsigned short* __restrict__ xl)
{
    int i = blockIdx.x * 256 + threadIdx.x;          // per float4, 786432 total
    float4 v = ((const float4*)x)[i];
    float vv[4] = {v.x, v.y, v.z, v.w};
    unsigned short h4[4], l4[4];
#pragma unroll
    for (int c = 0; c < 4; ++c) {
        unsigned short hb = f2bf(vv[c]);
        h4[c] = hb;
        l4[c] = f2bf(vv[c] - bf2f(hb));
    }
    ((ushort4*)xh)[i] = make_ushort4(h4[0], h4[1], h4[2], h4[3]);
    ((ushort4*)xl)[i] = make_ushort4(l4[0], l4[1], l4[2], l4[3]);
}

// ---------------------------------------------------------------------------
// W (f32 [8, 512, 64]) -> WT (bf16 [col=h*64+f][k=512]) hi + lo
__global__ __launch_bounds__(256) void k_convert_w(
    const float* __restrict__ W, unsigned short* __restrict__ wth,
    unsigned short* __restrict__ wtl)
{
    int tid = blockIdx.x * 256 + threadIdx.x;        // 262144
    int col = tid >> 9, k = tid & 511;
    int h = col >> 6, f = col & 63;
    float wv = W[(h * IN_F + k) * OUT_F + f];
    unsigned short hb = f2bf(wv);
    wth[tid] = hb;                                    // tid == col*512 + k
    wtl[tid] = f2bf(wv - bf2f(hb));
}

// ---------------------------------------------------------------------------
// adj (int32 [N,N]) -> bitmask u64 [N][N/64]
__global__ __launch_bounds__(256) void k_pack_adj(
    const int* __restrict__ adj, unsigned long long* __restrict__ bm)
{
    int idx = blockIdx.x * 256 + threadIdx.x;
    int pred = adj[idx] > 0;
    unsigned long long b = __ballot(pred);
    if ((threadIdx.x & 63) == 0) bm[idx >> 6] = b;
}

// ---------------------------------------------------------------------------
// Projection: h = x @ W per head via split-bf16 MFMA (xh@Wh + xh@Wl + xl@Wh).
// Writes hT (bf16 [h][f][n]) and s1/s2 (f32 [h][n]).
// Block = 4 waves; wave w covers rows rb*64+w*16..+16, all 64 cols of `head`.
__global__ __launch_bounds__(256) void k_proj(
    const unsigned short* __restrict__ xh, const unsigned short* __restrict__ xl,
    const unsigned short* __restrict__ wth, const unsigned short* __restrict__ wtl,
    const float* __restrict__ a1, const float* __restrict__ a2,
    unsigned short* __restrict__ hT, float* __restrict__ s1,
    float* __restrict__ s2)
{
    const int head = blockIdx.x & 7;
    const int rb = blockIdx.x >> 3;                  // 0..95
    const int w = threadIdx.x >> 6;
    const int lane = threadIdx.x & 63;
    const int r15 = lane & 15;
    const int g = lane >> 4;
    const int rowbase = rb * 64 + w * 16;
    const int rowA = rowbase + r15;

    f32x4 acc[4] = {};
    const unsigned short* xhp = xh + (size_t)rowA * IN_F + g * 8;
    const unsigned short* xlp = xl + (size_t)rowA * IN_F + g * 8;
    const int colbase = head * 64;

#pragma unroll 4
    for (int i = 0; i < 16; ++i) {
        const int k0 = i * 32;
        bf16x8 ah = *(const bf16x8*)(xhp + k0);
        bf16x8 al = *(const bf16x8*)(xlp + k0);
#pragma unroll
        for (int ct = 0; ct < 4; ++ct) {
            size_t boff = (size_t)(colbase + ct * 16 + r15) * IN_F + k0 + g * 8;
            bf16x8 bh = *(const bf16x8*)(wth + boff);
            bf16x8 bl = *(const bf16x8*)(wtl + boff);
            acc[ct] = __builtin_amdgcn_mfma_f32_16x16x32_bf16(ah, bh, acc[ct], 0, 0, 0);
            acc[ct] = __builtin_amdgcn_mfma_f32_16x16x32_bf16(ah, bl, acc[ct], 0, 0, 0);
            acc[ct] = __builtin_amdgcn_mfma_f32_16x16x32_bf16(al, bh, acc[ct], 0, 0, 0);
        }
    }

    // s1/s2: dot over f within the head (C/D: col = ct*16+r15, row = 4g+j)
    float a1v[4], a2v[4];
#pragma unroll
    for (int ct = 0; ct < 4; ++ct) {
        a1v[ct] = a1[head * 64 + ct * 16 + r15];
        a2v[ct] = a2[head * 64 + ct * 16 + r15];
    }
    float sp1[4] = {0, 0, 0, 0}, sp2[4] = {0, 0, 0, 0};
#pragma unroll
    for (int ct = 0; ct < 4; ++ct)
#pragma unroll
        for (int j = 0; j < 4; ++j) {
            sp1[j] += acc[ct][j] * a1v[ct];
            sp2[j] += acc[ct][j] * a2v[ct];
        }
#pragma unroll
    for (int d = 1; d < 16; d <<= 1) {
#pragma unroll
        for (int j = 0; j < 4; ++j) {
            sp1[j] += __shfl_xor(sp1[j], d);
            sp2[j] += __shfl_xor(sp2[j], d);
        }
    }
    if (r15 == 0) {
#pragma unroll
        for (int j = 0; j < 4; ++j) {
            int n = rowbase + g * 4 + j;
            s1[head * N_NODES + n] = sp1[j];
            s2[head * N_NODES + n] = sp2[j];
        }
    }
    // hT store: 4 consecutive n per lane per ct -> 8B packed store
#pragma unroll
    for (int ct = 0; ct < 4; ++ct) {
        ushort4 pk;
        pk.x = f2bf(acc[ct][0]);
        pk.y = f2bf(acc[ct][1]);
        pk.z = f2bf(acc[ct][2]);
        pk.w = f2bf(acc[ct][3]);
        int fcol = head * 64 + ct * 16 + r15;
        int n0 = rowbase + g * 4;
        *(ushort4*)(hT + (size_t)fcol * N_NODES + n0) = pk;
    }
}

// ---------------------------------------------------------------------------
// per-head max of s2 (unmasked upper bound for softmax stabilization)
__global__ __launch_bounds__(256) void k_s2max(
    const float* __restrict__ s2, float* __restrict__ s2m)
{
    const int h = blockIdx.x;
    float m = -3.0e38f;
    for (int i = threadIdx.x; i < N_NODES; i += 256)
        m = fmaxf(m, s2[h * N_NODES + i]);
#pragma unroll
    for (int d = 1; d < 64; d <<= 1) m = fmaxf(m, __shfl_xor(m, d));
    __shared__ float wm[4];
    if ((threadIdx.x & 63) == 0) wm[threadIdx.x >> 6] = m;
    __syncthreads();
    if (threadIdx.x == 0)
        s2m[h] = fmaxf(fmaxf(wm[0], wm[1]), fmaxf(wm[2], wm[3]));
}

// ---------------------------------------------------------------------------
// Flash attention over the bitmask. Block = (head, 64 Q-rows), 4 waves.
// Wave owns 16 rows; loops 96 m-tiles of 64; P built in regs, H from LDS.
__global__ __launch_bounds__(256) void k_flash(
    const unsigned short* __restrict__ hT, const float* __restrict__ s1,
    const float* __restrict__ s2, const float* __restrict__ s2m,
    const unsigned long long* __restrict__ bm, float* __restrict__ out)
{
    __shared__ float s2s[N_NODES];           // 24 KB
    __shared__ unsigned short sht[64][72];   // 9 KB, +8 pad (keeps 16B align)

    const int head = blockIdx.x / NTILES;
    const int rb = blockIdx.x % NTILES;
    const int tid = threadIdx.x;
    const int w = tid >> 6, lane = tid & 63, r15 = lane & 15, g = lane >> 4;
    const int r = rb * 64 + w * 16 + r15;    // this lane's score-row

    {   // stage s2[head] into LDS
        const float4* src = (const float4*)(s2 + head * N_NODES);
        float4* dst = (float4*)s2s;
        for (int i = tid; i < N_NODES / 4; i += 256) dst[i] = src[i];
    }
    const float s1r = s1[head * N_NODES + r];
    const float t0 = s1r + s2m[head];
    const float Mr = fmaxf(t0, ALPHA * t0);  // lrelu(s1r + max s2) >= row max
    const float c0 = -Mr * L2E;

    f32x4 acc[4] = {};
    float Lacc = 0.f;
    const unsigned short* hTh = hT + (size_t)head * 64 * N_NODES;
    const unsigned long long* bmr = bm + (size_t)r * NTILES;

    for (int t = 0; t < NTILES; ++t) {
        __syncthreads();
        {   // stage hT tile [64 f][64 m] -> sht
            int ff = tid >> 3;               // 0..31
            int c = tid & 7;
            const int m0 = t * 64 + c * 8;
#pragma unroll
            for (int rr = 0; rr < 2; ++rr) {
                int f2 = ff + rr * 32;
                int4 v = *(const int4*)(hTh + (size_t)f2 * N_NODES + m0);
                *(int4*)&sht[f2][c * 8] = v;
            }
        }
        __syncthreads();

        unsigned long long mask = bmr[t];
#pragma unroll
        for (int kk = 0; kk < 2; ++kk) {
            const int mloc = kk * 32 + g * 8;
            float4 sa = *(const float4*)&s2s[t * 64 + mloc];
            float4 sb = *(const float4*)&s2s[t * 64 + mloc + 4];
            unsigned int msel = (unsigned int)(mask >> mloc);
            float pv[8];
            float sv[8] = {sa.x, sa.y, sa.z, sa.w, sb.x, sb.y, sb.z, sb.w};
#pragma unroll
            for (int j = 0; j < 8; ++j) {
                float tt = s1r + sv[j];
                float lr = fmaxf(tt, ALPHA * tt);          // leaky relu
                float pe = exp2f(fmaf(lr, L2E, c0));       // exp(lr - Mr)
                pe = ((msel >> j) & 1u) ? pe : 0.0f;       // adjacency mask
                Lacc += pe;
                pv[j] = pe;
            }
            bf16x8 pa;
#pragma unroll
            for (int j = 0; j < 8; ++j) pa[j] = (short)f2bf(pv[j]);
#pragma unroll
            for (int ct = 0; ct < 4; ++ct) {
                bf16x8 hb = *(const bf16x8*)&sht[ct * 16 + r15][mloc];
                acc[ct] = __builtin_amdgcn_mfma_f32_16x16x32_bf16(pa, hb, acc[ct], 0, 0, 0);
            }
        }
    }

    // full row-sum: combine the 4 lane-groups
    Lacc += __shfl_xor(Lacc, 16);
    Lacc += __shfl_xor(Lacc, 32);

    // acc rows are 4g+j; fetch their denominators from lanes r15==4g+j
    float rinv[4];
#pragma unroll
    for (int j = 0; j < 4; ++j) {
        float Lj = __shfl(Lacc, g * 4 + j);
        rinv[j] = 1.0f / Lj;
    }

    const int nbase = rb * 64 + w * 16 + g * 4;
#pragma unroll
    for (int ct = 0; ct < 4; ++ct) {
#pragma unroll
        for (int j = 0; j < 4; ++j) {
            float v = acc[ct][j] * rinv[j];
            v = (v > 0.f) ? v : (expf(v) - 1.f);           // ELU
            out[(size_t)(nbase + j) * 512 + head * 64 + ct * 16 + r15] = v;
        }
    }
}

// ---------------------------------------------------------------------------
extern "C" void kernel_launch(void* const* d_in, const int* in_sizes, int n_in,
                              void* d_out, int out_size, void* d_ws, size_t ws_size,
                              hipStream_t stream)
{
    const float* x = (const float*)d_in[0];
    const int* adj = (const int*)d_in[1];
    const float* W = (const float*)d_in[2];
    const float* a1 = (const float*)d_in[3];
    const float* a2 = (const float*)d_in[4];
    float* out = (float*)d_out;

    char* ws = (char*)d_ws;
    size_t off = 0;
    auto take = [&](size_t bytes) {
        void* p = ws + off;
        off = (off + bytes + 255) & ~(size_t)255;
        return p;
    };
    unsigned short* xh  = (unsigned short*)take((size_t)N_NODES * IN_F * 2);
    unsigned short* xl  = (unsigned short*)take((size_t)N_NODES * IN_F * 2);
    unsigned short* wth = (unsigned short*)take((size_t)512 * 512 * 2);
    unsigned short* wtl = (unsigned short*)take((size_t)512 * 512 * 2);
    unsigned short* hT  = (unsigned short*)take((size_t)NH * 64 * N_NODES * 2);
    float* s1  = (float*)take((size_t)NH * N_NODES * 4);
    float* s2  = (float*)take((size_t)NH * N_NODES * 4);
    float* s2m = (float*)take(256);
    unsigned long long* bmask =
        (unsigned long long*)take((size_t)N_NODES * (N_NODES / 64) * 8);

    k_convert_x<<<dim3((N_NODES * IN_F / 4) / 256), dim3(256), 0, stream>>>(x, xh, xl);
    k_convert_w<<<dim3((512 * 512) / 256), dim3(256), 0, stream>>>(W, wth, wtl);
    k_pack_adj<<<dim3((N_NODES * N_NODES) / 256), dim3(256), 0, stream>>>(adj, bmask);
    k_proj<<<dim3(NH * (N_NODES / 64)), dim3(256), 0, stream>>>(
        xh, xl, wth, wtl, a1, a2, hT, s1, s2);
    k_s2max<<<dim3(NH), dim3(256), 0, stream>>>(s2, s2m);
    k_flash<<<dim3(NH * (N_NODES / 64)), dim3(256), 0, stream>>>(
        hT, s1, s2, s2m, bmask, out);
}

// Round 2
// 282.316 us; speedup vs baseline: 1.0699x; 1.0699x over previous
//
#include <hip/hip_runtime.h>
#include <hip/hip_bf16.h>
#include <stdint.h>

#define N_NODES 6144
#define IN_F    512
#define OUT_F   64
#define NH      8
#define ALPHA   0.2f
#define L2E     1.4426950408889634f
#define NTILES  (N_NODES / 64)   // 96

typedef __attribute__((ext_vector_type(8))) short bf16x8;
typedef __attribute__((ext_vector_type(4))) float f32x4;

__device__ __forceinline__ unsigned short f2bf(float f) {
    uint32_t u = __float_as_uint(f);
    u += 0x7fffu + ((u >> 16) & 1u);     // round-to-nearest-even
    return (unsigned short)(u >> 16);
}
__device__ __forceinline__ float bf2f(unsigned short h) {
    return __uint_as_float(((uint32_t)h) << 16);
}

// ---------------------------------------------------------------------------
// x (f32 [N, 512]) -> xh (bf16 hi) + xl (bf16 of residual), same layout
__global__ __launch_bounds__(256) void k_convert_x(
    const float* __restrict__ x, unsigned short* __restrict__ xh,
    unsigned short* __restrict__ xl)
{
    int i = blockIdx.x * 256 + threadIdx.x;          // per float4, 786432 total
    float4 v = ((const float4*)x)[i];
    float vv[4] = {v.x, v.y, v.z, v.w};
    unsigned short h4[4], l4[4];
#pragma unroll
    for (int c = 0; c < 4; ++c) {
        unsigned short hb = f2bf(vv[c]);
        h4[c] = hb;
        l4[c] = f2bf(vv[c] - bf2f(hb));
    }
    ((ushort4*)xh)[i] = make_ushort4(h4[0], h4[1], h4[2], h4[3]);
    ((ushort4*)xl)[i] = make_ushort4(l4[0], l4[1], l4[2], l4[3]);
}

// ---------------------------------------------------------------------------
// W (f32 [8, 512, 64]) -> WT (bf16 [col=h*64+f][k=512]) hi + lo
__global__ __launch_bounds__(256) void k_convert_w(
    const float* __restrict__ W, unsigned short* __restrict__ wth,
    unsigned short* __restrict__ wtl)
{
    int tid = blockIdx.x * 256 + threadIdx.x;        // 262144
    int col = tid >> 9, k = tid & 511;
    int h = col >> 6, f = col & 63;
    float wv = W[(h * IN_F + k) * OUT_F + f];
    unsigned short hb = f2bf(wv);
    wth[tid] = hb;                                    // tid == col*512 + k
    wtl[tid] = f2bf(wv - bf2f(hb));
}

// ---------------------------------------------------------------------------
// adj (int32 [N,N]) -> bitmask u64 [N][N/64]
__global__ __launch_bounds__(256) void k_pack_adj(
    const int* __restrict__ adj, unsigned long long* __restrict__ bm)
{
    int idx = blockIdx.x * 256 + threadIdx.x;
    int pred = adj[idx] > 0;
    unsigned long long b = __ballot(pred);
    if ((threadIdx.x & 63) == 0) bm[idx >> 6] = b;
}

// ---------------------------------------------------------------------------
// Projection: h = x @ W per head via split-bf16 MFMA (xh@Wh + xh@Wl + xl@Wh).
// Writes hT (bf16 [h][f][n]) and s1/s2 (f32 [h][n]).
__global__ __launch_bounds__(256) void k_proj(
    const unsigned short* __restrict__ xh, const unsigned short* __restrict__ xl,
    const unsigned short* __restrict__ wth, const unsigned short* __restrict__ wtl,
    const float* __restrict__ a1, const float* __restrict__ a2,
    unsigned short* __restrict__ hT, float* __restrict__ s1,
    float* __restrict__ s2)
{
    const int head = blockIdx.x & 7;
    const int rb = blockIdx.x >> 3;                  // 0..95
    const int w = threadIdx.x >> 6;
    const int lane = threadIdx.x & 63;
    const int r15 = lane & 15;
    const int g = lane >> 4;
    const int rowbase = rb * 64 + w * 16;
    const int rowA = rowbase + r15;

    f32x4 acc[4] = {};
    const unsigned short* xhp = xh + (size_t)rowA * IN_F + g * 8;
    const unsigned short* xlp = xl + (size_t)rowA * IN_F + g * 8;
    const int colbase = head * 64;

#pragma unroll 4
    for (int i = 0; i < 16; ++i) {
        const int k0 = i * 32;
        bf16x8 ah = *(const bf16x8*)(xhp + k0);
        bf16x8 al = *(const bf16x8*)(xlp + k0);
#pragma unroll
        for (int ct = 0; ct < 4; ++ct) {
            size_t boff = (size_t)(colbase + ct * 16 + r15) * IN_F + k0 + g * 8;
            bf16x8 bh = *(const bf16x8*)(wth + boff);
            bf16x8 bl = *(const bf16x8*)(wtl + boff);
            acc[ct] = __builtin_amdgcn_mfma_f32_16x16x32_bf16(ah, bh, acc[ct], 0, 0, 0);
            acc[ct] = __builtin_amdgcn_mfma_f32_16x16x32_bf16(ah, bl, acc[ct], 0, 0, 0);
            acc[ct] = __builtin_amdgcn_mfma_f32_16x16x32_bf16(al, bh, acc[ct], 0, 0, 0);
        }
    }

    // s1/s2: dot over f within the head (C/D: col = ct*16+r15, row = 4g+j)
    float a1v[4], a2v[4];
#pragma unroll
    for (int ct = 0; ct < 4; ++ct) {
        a1v[ct] = a1[head * 64 + ct * 16 + r15];
        a2v[ct] = a2[head * 64 + ct * 16 + r15];
    }
    float sp1[4] = {0, 0, 0, 0}, sp2[4] = {0, 0, 0, 0};
#pragma unroll
    for (int ct = 0; ct < 4; ++ct)
#pragma unroll
        for (int j = 0; j < 4; ++j) {
            sp1[j] += acc[ct][j] * a1v[ct];
            sp2[j] += acc[ct][j] * a2v[ct];
        }
#pragma unroll
    for (int d = 1; d < 16; d <<= 1) {
#pragma unroll
        for (int j = 0; j < 4; ++j) {
            sp1[j] += __shfl_xor(sp1[j], d);
            sp2[j] += __shfl_xor(sp2[j], d);
        }
    }
    if (r15 == 0) {
#pragma unroll
        for (int j = 0; j < 4; ++j) {
            int n = rowbase + g * 4 + j;
            s1[head * N_NODES + n] = sp1[j];
            s2[head * N_NODES + n] = sp2[j];
        }
    }
    // hT store: 4 consecutive n per lane per ct -> 8B packed store
#pragma unroll
    for (int ct = 0; ct < 4; ++ct) {
        ushort4 pk;
        pk.x = f2bf(acc[ct][0]);
        pk.y = f2bf(acc[ct][1]);
        pk.z = f2bf(acc[ct][2]);
        pk.w = f2bf(acc[ct][3]);
        int fcol = head * 64 + ct * 16 + r15;
        int n0 = rowbase + g * 4;
        *(ushort4*)(hT + (size_t)fcol * N_NODES + n0) = pk;
    }
}

// ---------------------------------------------------------------------------
// per-head max of s2 (unmasked upper bound for softmax stabilization)
__global__ __launch_bounds__(256) void k_s2max(
    const float* __restrict__ s2, float* __restrict__ s2m)
{
    const int h = blockIdx.x;
    float m = -3.0e38f;
    for (int i = threadIdx.x; i < N_NODES; i += 256)
        m = fmaxf(m, s2[h * N_NODES + i]);
#pragma unroll
    for (int d = 1; d < 64; d <<= 1) m = fmaxf(m, __shfl_xor(m, d));
    __shared__ float wm[4];
    if ((threadIdx.x & 63) == 0) wm[threadIdx.x >> 6] = m;
    __syncthreads();
    if (threadIdx.x == 0)
        s2m[h] = fmaxf(fmaxf(wm[0], wm[1]), fmaxf(wm[2], wm[3]));
}

// ---------------------------------------------------------------------------
// exp tables: E2p = exp2(s2*L2E), E2n = exp2(alpha*s2*L2E)  [H*N each]
__global__ __launch_bounds__(256) void k_tables(
    const float* __restrict__ s2, float* __restrict__ e2p,
    float* __restrict__ e2n)
{
    int i = blockIdx.x * 256 + threadIdx.x;          // H*N
    float v = s2[i];
    e2p[i] = exp2f(v * L2E);
    e2n[i] = exp2f(ALPHA * v * L2E);
}

// ---------------------------------------------------------------------------
// Flash attention v2: table-driven scores, no in-loop exp, cvt_pk pack,
// row-sum via ones-MFMA, double-buffered hT staging (1 barrier/tile).
__global__ __launch_bounds__(256) void k_flash(
    const unsigned short* __restrict__ hT, const float* __restrict__ s1,
    const float* __restrict__ s2m, const float* __restrict__ e2p,
    const float* __restrict__ e2n, const unsigned long long* __restrict__ bm,
    float* __restrict__ out)
{
    __shared__ unsigned short sht[2][64][72];        // 18.4 KB, pad 72

    const int head = blockIdx.x / NTILES;
    const int rb = blockIdx.x % NTILES;
    const int tid = threadIdx.x;
    const int w = tid >> 6, lane = tid & 63, r15 = lane & 15, g = lane >> 4;
    const int r = rb * 64 + w * 16 + r15;            // this lane's score-row

    const float s1r = s1[head * N_NODES + r];
    const float t0 = s1r + s2m[head];
    const float Mr = fmaxf(t0, ALPHA * t0);          // >= row max of lrelu
    const float E1p = exp2f((s1r - Mr) * L2E);
    const float E1n = exp2f((ALPHA * s1r - Mr) * L2E);
    const float Tr  = exp2f(-s1r * L2E);             // t>=0 <=> E2p[m] >= Tr

    const float* __restrict__ e2ph = e2p + head * N_NODES;
    const float* __restrict__ e2nh = e2n + head * N_NODES;
    const unsigned short* __restrict__ hTh = hT + (size_t)head * 64 * N_NODES;
    const unsigned long long* __restrict__ bmr = bm + (size_t)r * NTILES;

    f32x4 acc[4] = {};
    f32x4 accS = {};                                  // row sums via ones-MFMA
    const bf16x8 vones = {(short)0x3F80, (short)0x3F80, (short)0x3F80,
                          (short)0x3F80, (short)0x3F80, (short)0x3F80,
                          (short)0x3F80, (short)0x3F80};

    const int ff = tid >> 3;                          // 0..31 staging row
    const int cc = tid & 7;                           // staging col-chunk

    {   // prologue: stage tile 0 into buffer 0
        int4 v0 = *(const int4*)(hTh + (size_t)ff * N_NODES + cc * 8);
        int4 v1 = *(const int4*)(hTh + (size_t)(ff + 32) * N_NODES + cc * 8);
        *(int4*)&sht[0][ff][cc * 8] = v0;
        *(int4*)&sht[0][ff + 32][cc * 8] = v1;
    }
    __syncthreads();

    for (int t = 0; t < NTILES; ++t) {
        const int cur = t & 1;
        // issue next-tile loads early (T14): latency hides under compute
        const int tn = (t + 1 < NTILES) ? (t + 1) : t;
        const int m0n = tn * 64 + cc * 8;
        int4 p0 = *(const int4*)(hTh + (size_t)ff * N_NODES + m0n);
        int4 p1 = *(const int4*)(hTh + (size_t)(ff + 32) * N_NODES + m0n);

        const unsigned long long mask = bmr[t];
        const unsigned short(*buf)[72] = sht[cur];

#pragma unroll
        for (int kk = 0; kk < 2; ++kk) {
            const int mbase = t * 64 + kk * 32 + g * 8;
            float4 ea = *(const float4*)(e2ph + mbase);
            float4 eb = *(const float4*)(e2ph + mbase + 4);
            float4 na = *(const float4*)(e2nh + mbase);
            float4 nb = *(const float4*)(e2nh + mbase + 4);
            const unsigned int msel = (unsigned int)(mask >> (kk * 32 + g * 8));
            float ep[8] = {ea.x, ea.y, ea.z, ea.w, eb.x, eb.y, eb.z, eb.w};
            float en[8] = {na.x, na.y, na.z, na.w, nb.x, nb.y, nb.z, nb.w};

            uint32_t pk[4];
#pragma unroll
            for (int j2 = 0; j2 < 4; ++j2) {
                float pe[2];
#pragma unroll
                for (int h2 = 0; h2 < 2; ++h2) {
                    const int j = j2 * 2 + h2;
                    const bool pos = ep[j] >= Tr;          // sign of t
                    float e1s = pos ? E1p : E1n;
                    float e2s = pos ? ep[j] : en[j];
                    e1s = (msel & (1u << j)) ? e1s : 0.0f; // adjacency
                    pe[h2] = e1s * e2s;
                }
                asm("v_cvt_pk_bf16_f32 %0, %1, %2"
                    : "=v"(pk[j2]) : "v"(pe[0]), "v"(pe[1]));
            }
            union { uint32_t u[4]; bf16x8 v; } pun;
            pun.u[0] = pk[0]; pun.u[1] = pk[1];
            pun.u[2] = pk[2]; pun.u[3] = pk[3];
            const bf16x8 pa = pun.v;

            accS = __builtin_amdgcn_mfma_f32_16x16x32_bf16(pa, vones, accS, 0, 0, 0);
            const int mloc = kk * 32 + g * 8;
#pragma unroll
            for (int ct = 0; ct < 4; ++ct) {
                bf16x8 hb = *(const bf16x8*)&buf[ct * 16 + r15][mloc];
                acc[ct] = __builtin_amdgcn_mfma_f32_16x16x32_bf16(pa, hb, acc[ct], 0, 0, 0);
            }
        }

        // write prefetched tile into the other buffer, then single barrier
        *(int4*)&sht[cur ^ 1][ff][cc * 8] = p0;
        *(int4*)&sht[cur ^ 1][ff + 32][cc * 8] = p1;
        __syncthreads();
    }

    // denominators live in-lane: accS[j] is the row sum for row 4g+j
    float rinv[4];
#pragma unroll
    for (int j = 0; j < 4; ++j) rinv[j] = 1.0f / accS[j];

    const int nbase = rb * 64 + w * 16 + g * 4;
#pragma unroll
    for (int ct = 0; ct < 4; ++ct) {
#pragma unroll
        for (int j = 0; j < 4; ++j) {
            float v = acc[ct][j] * rinv[j];
            v = (v > 0.f) ? v : (expf(v) - 1.f);           // ELU
            out[(size_t)(nbase + j) * 512 + head * 64 + ct * 16 + r15] = v;
        }
    }
}

// ---------------------------------------------------------------------------
extern "C" void kernel_launch(void* const* d_in, const int* in_sizes, int n_in,
                              void* d_out, int out_size, void* d_ws, size_t ws_size,
                              hipStream_t stream)
{
    const float* x = (const float*)d_in[0];
    const int* adj = (const int*)d_in[1];
    const float* W = (const float*)d_in[2];
    const float* a1 = (const float*)d_in[3];
    const float* a2 = (const float*)d_in[4];
    float* out = (float*)d_out;

    char* ws = (char*)d_ws;
    size_t off = 0;
    auto take = [&](size_t bytes) {
        void* p = ws + off;
        off = (off + bytes + 255) & ~(size_t)255;
        return p;
    };
    unsigned short* xh  = (unsigned short*)take((size_t)N_NODES * IN_F * 2);
    unsigned short* xl  = (unsigned short*)take((size_t)N_NODES * IN_F * 2);
    unsigned short* wth = (unsigned short*)take((size_t)512 * 512 * 2);
    unsigned short* wtl = (unsigned short*)take((size_t)512 * 512 * 2);
    unsigned short* hT  = (unsigned short*)take((size_t)NH * 64 * N_NODES * 2);
    float* s1  = (float*)take((size_t)NH * N_NODES * 4);
    float* s2  = (float*)take((size_t)NH * N_NODES * 4);
    float* s2m = (float*)take(256);
    float* e2p = (float*)take((size_t)NH * N_NODES * 4);
    float* e2n = (float*)take((size_t)NH * N_NODES * 4);
    unsigned long long* bmask =
        (unsigned long long*)take((size_t)N_NODES * (N_NODES / 64) * 8);

    k_convert_x<<<dim3((N_NODES * IN_F / 4) / 256), dim3(256), 0, stream>>>(x, xh, xl);
    k_convert_w<<<dim3((512 * 512) / 256), dim3(256), 0, stream>>>(W, wth, wtl);
    k_pack_adj<<<dim3((N_NODES * N_NODES) / 256), dim3(256), 0, stream>>>(adj, bmask);
    k_proj<<<dim3(NH * (N_NODES / 64)), dim3(256), 0, stream>>>(
        xh, xl, wth, wtl, a1, a2, hT, s1, s2);
    k_s2max<<<dim3(NH), dim3(256), 0, stream>>>(s2, s2m);
    k_tables<<<dim3(NH * N_NODES / 256), dim3(256), 0, stream>>>(s2, e2p, e2n);
    k_flash<<<dim3(NH * NTILES), dim3(256), 0, stream>>>(
        hT, s1, s2m, e2p, e2n, bmask, out);
}

// Round 3
// 209.864 us; speedup vs baseline: 1.4393x; 1.3452x over previous
//
#include <hip/hip_runtime.h>
#include <hip/hip_bf16.h>
#include <stdint.h>

#define N_NODES 6144
#define IN_F    512
#define OUT_F   64
#define NH      8
#define ALPHA   0.2f
#define L2E     1.4426950408889634f
#define NTILES  (N_NODES / 64)   // 96

typedef __attribute__((ext_vector_type(8))) short bf16x8;
typedef __attribute__((ext_vector_type(4))) float f32x4;

#define MFMA16(a, b, c) __builtin_amdgcn_mfma_f32_16x16x32_bf16(a, b, c, 0, 0, 0)

__device__ __forceinline__ unsigned short f2bf(float f) {
    uint32_t u = __float_as_uint(f);
    u += 0x7fffu + ((u >> 16) & 1u);     // round-to-nearest-even
    return (unsigned short)(u >> 16);
}
__device__ __forceinline__ float bf2f(unsigned short h) {
    return __uint_as_float(((uint32_t)h) << 16);
}

// ---------------------------------------------------------------------------
// x (f32 [N, 512]) -> xh (bf16 hi) + xl (bf16 of residual), same layout
__global__ __launch_bounds__(256) void k_convert_x(
    const float* __restrict__ x, unsigned short* __restrict__ xh,
    unsigned short* __restrict__ xl)
{
    int i = blockIdx.x * 256 + threadIdx.x;          // per float4, 786432 total
    float4 v = ((const float4*)x)[i];
    float vv[4] = {v.x, v.y, v.z, v.w};
    unsigned short h4[4], l4[4];
#pragma unroll
    for (int c = 0; c < 4; ++c) {
        unsigned short hb = f2bf(vv[c]);
        h4[c] = hb;
        l4[c] = f2bf(vv[c] - bf2f(hb));
    }
    ((ushort4*)xh)[i] = make_ushort4(h4[0], h4[1], h4[2], h4[3]);
    ((ushort4*)xl)[i] = make_ushort4(l4[0], l4[1], l4[2], l4[3]);
}

// ---------------------------------------------------------------------------
// W (f32 [8, 512, 64]) -> WT (bf16 [col=h*64+f][k=512]) hi + lo
__global__ __launch_bounds__(256) void k_convert_w(
    const float* __restrict__ W, unsigned short* __restrict__ wth,
    unsigned short* __restrict__ wtl)
{
    int tid = blockIdx.x * 256 + threadIdx.x;        // 262144
    int col = tid >> 9, k = tid & 511;
    int h = col >> 6, f = col & 63;
    float wv = W[(h * IN_F + k) * OUT_F + f];
    unsigned short hb = f2bf(wv);
    wth[tid] = hb;                                    // tid == col*512 + k
    wtl[tid] = f2bf(wv - bf2f(hb));
}

// ---------------------------------------------------------------------------
// adj (int32 [N,N]) -> bitmask u64 [N][N/64], grid-stride
__global__ __launch_bounds__(256) void k_pack_adj(
    const int* __restrict__ adj, unsigned long long* __restrict__ bm)
{
    const int stride = gridDim.x * 256;
    for (int idx = blockIdx.x * 256 + threadIdx.x; idx < N_NODES * N_NODES;
         idx += stride) {
        unsigned long long b = __ballot(adj[idx] > 0);
        if ((threadIdx.x & 63) == 0) bm[idx >> 6] = b;
    }
}

// ---------------------------------------------------------------------------
// Projection: h = x @ W per head via split-bf16 MFMA (xh@Wh + xh@Wl + xl@Wh).
__global__ __launch_bounds__(256) void k_proj(
    const unsigned short* __restrict__ xh, const unsigned short* __restrict__ xl,
    const unsigned short* __restrict__ wth, const unsigned short* __restrict__ wtl,
    const float* __restrict__ a1, const float* __restrict__ a2,
    unsigned short* __restrict__ hT, float* __restrict__ s1,
    float* __restrict__ s2)
{
    const int head = blockIdx.x & 7;
    const int rb = blockIdx.x >> 3;                  // 0..95
    const int w = threadIdx.x >> 6;
    const int lane = threadIdx.x & 63;
    const int r15 = lane & 15;
    const int g = lane >> 4;
    const int rowbase = rb * 64 + w * 16;
    const int rowA = rowbase + r15;

    f32x4 acc[4] = {};
    const unsigned short* xhp = xh + (size_t)rowA * IN_F + g * 8;
    const unsigned short* xlp = xl + (size_t)rowA * IN_F + g * 8;
    const int colbase = head * 64;

#pragma unroll 4
    for (int i = 0; i < 16; ++i) {
        const int k0 = i * 32;
        bf16x8 ah = *(const bf16x8*)(xhp + k0);
        bf16x8 al = *(const bf16x8*)(xlp + k0);
#pragma unroll
        for (int ct = 0; ct < 4; ++ct) {
            size_t boff = (size_t)(colbase + ct * 16 + r15) * IN_F + k0 + g * 8;
            bf16x8 bh = *(const bf16x8*)(wth + boff);
            bf16x8 bl = *(const bf16x8*)(wtl + boff);
            acc[ct] = MFMA16(ah, bh, acc[ct]);
            acc[ct] = MFMA16(ah, bl, acc[ct]);
            acc[ct] = MFMA16(al, bh, acc[ct]);
        }
    }

    float a1v[4], a2v[4];
#pragma unroll
    for (int ct = 0; ct < 4; ++ct) {
        a1v[ct] = a1[head * 64 + ct * 16 + r15];
        a2v[ct] = a2[head * 64 + ct * 16 + r15];
    }
    float sp1[4] = {0, 0, 0, 0}, sp2[4] = {0, 0, 0, 0};
#pragma unroll
    for (int ct = 0; ct < 4; ++ct)
#pragma unroll
        for (int j = 0; j < 4; ++j) {
            sp1[j] += acc[ct][j] * a1v[ct];
            sp2[j] += acc[ct][j] * a2v[ct];
        }
#pragma unroll
    for (int d = 1; d < 16; d <<= 1) {
#pragma unroll
        for (int j = 0; j < 4; ++j) {
            sp1[j] += __shfl_xor(sp1[j], d);
            sp2[j] += __shfl_xor(sp2[j], d);
        }
    }
    if (r15 == 0) {
#pragma unroll
        for (int j = 0; j < 4; ++j) {
            int n = rowbase + g * 4 + j;
            s1[head * N_NODES + n] = sp1[j];
            s2[head * N_NODES + n] = sp2[j];
        }
    }
#pragma unroll
    for (int ct = 0; ct < 4; ++ct) {
        ushort4 pk;
        pk.x = f2bf(acc[ct][0]);
        pk.y = f2bf(acc[ct][1]);
        pk.z = f2bf(acc[ct][2]);
        pk.w = f2bf(acc[ct][3]);
        int fcol = head * 64 + ct * 16 + r15;
        int n0 = rowbase + g * 4;
        *(ushort4*)(hT + (size_t)fcol * N_NODES + n0) = pk;
    }
}

// ---------------------------------------------------------------------------
// per-head max of s2 (unmasked upper bound for softmax stabilization)
__global__ __launch_bounds__(256) void k_s2max(
    const float* __restrict__ s2, float* __restrict__ s2m)
{
    const int h = blockIdx.x;
    float m = -3.0e38f;
    for (int i = threadIdx.x; i < N_NODES; i += 256)
        m = fmaxf(m, s2[h * N_NODES + i]);
#pragma unroll
    for (int d = 1; d < 64; d <<= 1) m = fmaxf(m, __shfl_xor(m, d));
    __shared__ float wm[4];
    if ((threadIdx.x & 63) == 0) wm[threadIdx.x >> 6] = m;
    __syncthreads();
    if (threadIdx.x == 0)
        s2m[h] = fmaxf(fmaxf(wm[0], wm[1]), fmaxf(wm[2], wm[3]));
}

// ---------------------------------------------------------------------------
// tables pre-scaled by s2max so every factor <= 1 (no overflow possible):
//   e2p = exp(s2 - s2m), e2n = exp(alpha*(s2 - s2m))
__global__ __launch_bounds__(256) void k_tables(
    const float* __restrict__ s2, const float* __restrict__ s2m,
    float* __restrict__ e2p, float* __restrict__ e2n)
{
    int i = blockIdx.x * 256 + threadIdx.x;          // H*N
    int h = i / N_NODES;
    float v = s2[i] - s2m[h];
    e2p[i] = exp2f(v * L2E);
    e2n[i] = exp2f(ALPHA * v * L2E);
}

// ---------------------------------------------------------------------------
// P-fragment builder: p = max(E1p*e2p[m], E1n*e2n[m]) masked by adjacency.
__device__ __forceinline__ bf16x8 mk_pa(float4 ea, float4 eb, float4 na,
                                        float4 nb, float e1p, float e1n,
                                        uint32_t msel)
{
    float ep[8] = {ea.x, ea.y, ea.z, ea.w, eb.x, eb.y, eb.z, eb.w};
    float en[8] = {na.x, na.y, na.z, na.w, nb.x, nb.y, nb.z, nb.w};
    uint32_t pk[4];
#define PAIR(J2, B0, B1)                                                      \
    {                                                                         \
        float p0 = fmaxf(e1p * ep[2 * J2],     e1n * en[2 * J2]);             \
        float p1 = fmaxf(e1p * ep[2 * J2 + 1], e1n * en[2 * J2 + 1]);         \
        int mb0, mb1;                                                         \
        asm("v_bfe_i32 %0, %1, " #B0 ", 1" : "=v"(mb0) : "v"(msel));          \
        asm("v_bfe_i32 %0, %1, " #B1 ", 1" : "=v"(mb1) : "v"(msel));          \
        p0 = __uint_as_float(__float_as_uint(p0) & (uint32_t)mb0);            \
        p1 = __uint_as_float(__float_as_uint(p1) & (uint32_t)mb1);            \
        asm("v_cvt_pk_bf16_f32 %0, %1, %2" : "=v"(pk[J2]) : "v"(p0), "v"(p1));\
    }
    PAIR(0, 0, 1)
    PAIR(1, 2, 3)
    PAIR(2, 4, 5)
    PAIR(3, 6, 7)
#undef PAIR
    union { uint32_t u[4]; bf16x8 v; } pun;
    pun.u[0] = pk[0]; pun.u[1] = pk[1]; pun.u[2] = pk[2]; pun.u[3] = pk[3];
    return pun.v;
}

struct Pf {                          // one-tile-ahead register prefetch
    float4 ea0, eb0, na0, nb0;       // tables kk=0
    float4 ea1, eb1, na1, nb1;       // tables kk=1
    unsigned long long m0, m1;       // adjacency masks per row-group
};

// ---------------------------------------------------------------------------
// Flash attention v3: 128 threads (2 waves), 64 rows/block, 2 row-groups/wave
// (hb LDS fragments reused 2x), XOR-swizzled LDS (conflict-free), max-identity
// scores (5 VALU/score), full reg-prefetch one tile ahead.
__global__ __launch_bounds__(128) void k_flash(
    const unsigned short* __restrict__ hT, const float* __restrict__ s1,
    const float* __restrict__ s2m, const float* __restrict__ e2p,
    const float* __restrict__ e2n, const unsigned long long* __restrict__ bm,
    float* __restrict__ out)
{
    __shared__ unsigned short sht[2][64][64];        // 16 KB, XOR-swizzled

    const int head = blockIdx.x / NTILES;
    const int rb = blockIdx.x % NTILES;
    const int tid = threadIdx.x;
    const int w = tid >> 6, lane = tid & 63, r15 = lane & 15, g = lane >> 4;
    const int r7 = r15 & 7;

    // two row-groups per wave: rows rA (grp0) and rA+16 (grp1)
    const int rA = rb * 64 + w * 32 + r15;
    const int rB = rA + 16;
    const float s2mh = s2m[head];
    const float s1A = s1[head * N_NODES + rA];
    const float s1B = s1[head * N_NODES + rB];
    const float t0A = s1A + s2mh, t0B = s1B + s2mh;
    const float MrA = fmaxf(t0A, ALPHA * t0A);
    const float MrB = fmaxf(t0B, ALPHA * t0B);
    const float E1pA = exp2f((t0A - MrA) * L2E);
    const float E1nA = exp2f((ALPHA * t0A - MrA) * L2E);
    const float E1pB = exp2f((t0B - MrB) * L2E);
    const float E1nB = exp2f((ALPHA * t0B - MrB) * L2E);

    const float* __restrict__ e2ph = e2p + head * N_NODES;
    const float* __restrict__ e2nh = e2n + head * N_NODES;
    const unsigned short* __restrict__ hTh = hT + (size_t)head * 64 * N_NODES;
    const unsigned long long* __restrict__ bmr0 = bm + (size_t)rA * NTILES;
    const unsigned long long* __restrict__ bmr1 = bm + (size_t)rB * NTILES;

    f32x4 accA[4] = {}, accB[4] = {};
    f32x4 accSA = {}, accSB = {};
    const bf16x8 vones = {(short)0x3F80, (short)0x3F80, (short)0x3F80,
                          (short)0x3F80, (short)0x3F80, (short)0x3F80,
                          (short)0x3F80, (short)0x3F80};

    // staging geometry: 128 threads x 4 int4 = 8 KB tile
    const int fr = tid >> 3;                          // 0..15
    const int cc = tid & 7;
    const int wcol = ((cc ^ (fr & 7)) << 3);          // swizzled col (shorts)

    {   // prologue: stage tile 0 directly
#pragma unroll
        for (int q = 0; q < 4; ++q) {
            int4 v = *(const int4*)(hTh + (size_t)(fr + q * 16) * N_NODES + cc * 8);
            *(int4*)&sht[0][fr + q * 16][wcol] = v;
        }
    }
    Pf A, B;
    {   // prologue: prefetch tile-0 tables + masks
        A.m0 = bmr0[0];
        A.m1 = bmr1[0];
        const int mb0 = g * 8;
        A.ea0 = *(const float4*)(e2ph + mb0);
        A.eb0 = *(const float4*)(e2ph + mb0 + 4);
        A.na0 = *(const float4*)(e2nh + mb0);
        A.nb0 = *(const float4*)(e2nh + mb0 + 4);
        A.ea1 = *(const float4*)(e2ph + mb0 + 32);
        A.eb1 = *(const float4*)(e2ph + mb0 + 36);
        A.na1 = *(const float4*)(e2nh + mb0 + 32);
        A.nb1 = *(const float4*)(e2nh + mb0 + 36);
    }
    __syncthreads();

    auto body = [&](int t, Pf& C, Pf& Nx) {
        const int cur = t & 1;
        const int tn = (t + 1 < NTILES) ? (t + 1) : (NTILES - 1);
        // prefetch next tile: staging (local), masks + tables (into Nx)
        int4 st0, st1, st2, st3;
        {
            const int m0n = tn * 64 + cc * 8;
            st0 = *(const int4*)(hTh + (size_t)(fr)*N_NODES + m0n);
            st1 = *(const int4*)(hTh + (size_t)(fr + 16) * N_NODES + m0n);
            st2 = *(const int4*)(hTh + (size_t)(fr + 32) * N_NODES + m0n);
            st3 = *(const int4*)(hTh + (size_t)(fr + 48) * N_NODES + m0n);
            Nx.m0 = bmr0[tn];
            Nx.m1 = bmr1[tn];
            const int mb0 = tn * 64 + g * 8;
            Nx.ea0 = *(const float4*)(e2ph + mb0);
            Nx.eb0 = *(const float4*)(e2ph + mb0 + 4);
            Nx.na0 = *(const float4*)(e2nh + mb0);
            Nx.nb0 = *(const float4*)(e2nh + mb0 + 4);
            Nx.ea1 = *(const float4*)(e2ph + mb0 + 32);
            Nx.eb1 = *(const float4*)(e2ph + mb0 + 36);
            Nx.na1 = *(const float4*)(e2nh + mb0 + 32);
            Nx.nb1 = *(const float4*)(e2nh + mb0 + 36);
        }
        const unsigned short(*buf)[64] = sht[cur];

        // kk = 0
        {
            uint32_t msA = (uint32_t)(C.m0 >> (g * 8));
            uint32_t msB = (uint32_t)(C.m1 >> (g * 8));
            bf16x8 paA = mk_pa(C.ea0, C.eb0, C.na0, C.nb0, E1pA, E1nA, msA);
            bf16x8 paB = mk_pa(C.ea0, C.eb0, C.na0, C.nb0, E1pB, E1nB, msB);
            accSA = MFMA16(paA, vones, accSA);
            accSB = MFMA16(paB, vones, accSB);
            const int rcol = ((g ^ r7) << 3);
#pragma unroll
            for (int ct = 0; ct < 4; ++ct) {
                bf16x8 hb = *(const bf16x8*)&buf[ct * 16 + r15][rcol];
                accA[ct] = MFMA16(paA, hb, accA[ct]);
                accB[ct] = MFMA16(paB, hb, accB[ct]);
            }
        }
        // kk = 1
        {
            uint32_t msA = (uint32_t)(C.m0 >> (32 + g * 8));
            uint32_t msB = (uint32_t)(C.m1 >> (32 + g * 8));
            bf16x8 paA = mk_pa(C.ea1, C.eb1, C.na1, C.nb1, E1pA, E1nA, msA);
            bf16x8 paB = mk_pa(C.ea1, C.eb1, C.na1, C.nb1, E1pB, E1nB, msB);
            accSA = MFMA16(paA, vones, accSA);
            accSB = MFMA16(paB, vones, accSB);
            const int rcol = (((4 + g) ^ r7) << 3);
#pragma unroll
            for (int ct = 0; ct < 4; ++ct) {
                bf16x8 hb = *(const bf16x8*)&buf[ct * 16 + r15][rcol];
                accA[ct] = MFMA16(paA, hb, accA[ct]);
                accB[ct] = MFMA16(paB, hb, accB[ct]);
            }
        }

        // write next tile into other buffer, single barrier
        const int bufn = cur ^ 1;
        *(int4*)&sht[bufn][fr][wcol] = st0;
        *(int4*)&sht[bufn][fr + 16][wcol] = st1;
        *(int4*)&sht[bufn][fr + 32][wcol] = st2;
        *(int4*)&sht[bufn][fr + 48][wcol] = st3;
        __syncthreads();
    };

    for (int t = 0; t < NTILES; t += 2) {
        body(t, A, B);
        body(t + 1, B, A);
    }

    float rinvA[4], rinvB[4];
#pragma unroll
    for (int j = 0; j < 4; ++j) {
        rinvA[j] = 1.0f / accSA[j];
        rinvB[j] = 1.0f / accSB[j];
    }
    const int fcb = head * 64;
    const int nA = rb * 64 + w * 32 + g * 4;
    const int nB = nA + 16;
#pragma unroll
    for (int ct = 0; ct < 4; ++ct) {
#pragma unroll
        for (int j = 0; j < 4; ++j) {
            float vA = accA[ct][j] * rinvA[j];
            vA = (vA > 0.f) ? vA : (expf(vA) - 1.f);
            out[(size_t)(nA + j) * 512 + fcb + ct * 16 + r15] = vA;
            float vB = accB[ct][j] * rinvB[j];
            vB = (vB > 0.f) ? vB : (expf(vB) - 1.f);
            out[(size_t)(nB + j) * 512 + fcb + ct * 16 + r15] = vB;
        }
    }
}

// ---------------------------------------------------------------------------
extern "C" void kernel_launch(void* const* d_in, const int* in_sizes, int n_in,
                              void* d_out, int out_size, void* d_ws, size_t ws_size,
                              hipStream_t stream)
{
    const float* x = (const float*)d_in[0];
    const int* adj = (const int*)d_in[1];
    const float* W = (const float*)d_in[2];
    const float* a1 = (const float*)d_in[3];
    const float* a2 = (const float*)d_in[4];
    float* out = (float*)d_out;

    char* ws = (char*)d_ws;
    size_t off = 0;
    auto take = [&](size_t bytes) {
        void* p = ws + off;
        off = (off + bytes + 255) & ~(size_t)255;
        return p;
    };
    unsigned short* xh  = (unsigned short*)take((size_t)N_NODES * IN_F * 2);
    unsigned short* xl  = (unsigned short*)take((size_t)N_NODES * IN_F * 2);
    unsigned short* wth = (unsigned short*)take((size_t)512 * 512 * 2);
    unsigned short* wtl = (unsigned short*)take((size_t)512 * 512 * 2);
    unsigned short* hT  = (unsigned short*)take((size_t)NH * 64 * N_NODES * 2);
    float* s1  = (float*)take((size_t)NH * N_NODES * 4);
    float* s2  = (float*)take((size_t)NH * N_NODES * 4);
    float* s2m = (float*)take(256);
    float* e2p = (float*)take((size_t)NH * N_NODES * 4);
    float* e2n = (float*)take((size_t)NH * N_NODES * 4);
    unsigned long long* bmask =
        (unsigned long long*)take((size_t)N_NODES * (N_NODES / 64) * 8);

    k_convert_x<<<dim3((N_NODES * IN_F / 4) / 256), dim3(256), 0, stream>>>(x, xh, xl);
    k_convert_w<<<dim3((512 * 512) / 256), dim3(256), 0, stream>>>(W, wth, wtl);
    k_pack_adj<<<dim3(2048), dim3(256), 0, stream>>>(adj, bmask);
    k_proj<<<dim3(NH * (N_NODES / 64)), dim3(256), 0, stream>>>(
        xh, xl, wth, wtl, a1, a2, hT, s1, s2);
    k_s2max<<<dim3(NH), dim3(256), 0, stream>>>(s2, s2m);
    k_tables<<<dim3(NH * N_NODES / 256), dim3(256), 0, stream>>>(s2, s2m, e2p, e2n);
    k_flash<<<dim3(NH * NTILES), dim3(128), 0, stream>>>(
        hT, s1, s2m, e2p, e2n, bmask, out);
}